// Round 1
// baseline (205.950 us; speedup 1.0000x reference)
//
#include <hip/hip_runtime.h>
#include <math.h>

// Problem constants (from reference)
#define Hh   4
#define Bb   8
#define Qq   64
#define Kk   256
#define Dd   256
#define Nn   (Bb * Qq)          // 512
#define GNf  16.0f
#define EPSf 1e-5f

#define SKV  832                // KVb row stride: [k(256)|v(256)|p(256)|r(4)|pad]
#define SCB  1088               // Cb  row stride: [q(256)|k|v|p|r(4)|pad]

// ---------------------------------------------------------------------------
// 64-lane wave reduction (sum), result broadcast to all lanes
__device__ __forceinline__ float wred(float x) {
#pragma unroll
    for (int off = 32; off > 0; off >>= 1)
        x += __shfl_xor(x, off, 64);
    return x;
}

// ---------------------------------------------------------------------------
// prep: Wg = W_gk1 @ W_gk2  (256 x 256).  One block per output row (256 cols).
__global__ __launch_bounds__(256) void prep(
    const float* __restrict__ Wg1, const float* __restrict__ Wg2,
    float* __restrict__ Wg)
{
    const int e = blockIdx.x * 256 + threadIdx.x;   // < 65536
    const int k = e >> 8, c = e & 255;
    float s = 0.f;
#pragma unroll
    for (int i = 0; i < 16; ++i)
        s = fmaf(Wg1[k * 16 + i], Wg2[i * 256 + c], s);
    Wg[e] = s;
}

// ---------------------------------------------------------------------------
// Shared gemm tile: C(64 x 128) = A(64 x 256) @ B(256 x 128-slice).
// 256 threads as 16x16, micro-tile 4 rows x (4+4) cols.
// As stored TRANSPOSED As[k][m] with 68-float pitch (16B-aligned rows) and
// Ws[k][c] with 136-float pitch -> inner loop is pure ds_read_b128 + fma.
// Global loads for iteration k0+16 are issued before the compute of k0.
__device__ __forceinline__ void gemm_tile(
    const float* __restrict__ A, int lda, int Mv,
    const float* __restrict__ B, int ldb, int bn,
    float* __restrict__ C, int ldc)
{
    __shared__ float As[16][68];
    __shared__ float Ws[16][136];
    const int tid = threadIdx.x;
    const int ty = tid >> 4, tx = tid & 15;
    const int am = tid >> 2, ak = (tid & 3) << 2;   // A-stage: row am, k ak..ak+3
    const int wk = tid >> 4, wc = (tid & 15) << 3;  // B-stage: k wk, cols wc..wc+7
    const int ams = (am < Mv) ? am : (Mv - 1);      // clamp for short regions

    float acc[4][8] = {};

    const float* aptr = A + (size_t)ams * lda + ak;
    const float* bptr = B + (size_t)wk * ldb + bn + wc;
    float4 av  = *(const float4*)(aptr);
    float4 bv0 = *(const float4*)(bptr);
    float4 bv1 = *(const float4*)(bptr + 4);

    for (int k0 = 0; k0 < 256; k0 += 16) {
        __syncthreads();
        As[ak + 0][am] = av.x;
        As[ak + 1][am] = av.y;
        As[ak + 2][am] = av.z;
        As[ak + 3][am] = av.w;
        *(float4*)&Ws[wk][wc]     = bv0;
        *(float4*)&Ws[wk][wc + 4] = bv1;
        __syncthreads();
        if (k0 + 16 < 256) {        // prefetch next tile while computing this one
            av  = *(const float4*)(aptr + k0 + 16);
            bv0 = *(const float4*)(bptr + (size_t)(k0 + 16) * ldb);
            bv1 = *(const float4*)(bptr + (size_t)(k0 + 16) * ldb + 4);
        }
#pragma unroll
        for (int kk = 0; kk < 16; ++kk) {
            const float4 a4 = *(const float4*)&As[kk][ty << 2];
            const float4 w0 = *(const float4*)&Ws[kk][tx << 2];        // cols tx*4..+3
            const float4 w1 = *(const float4*)&Ws[kk][64 + (tx << 2)]; // cols 64+tx*4..+3
            const float a_[4] = {a4.x, a4.y, a4.z, a4.w};
            const float w_[8] = {w0.x, w0.y, w0.z, w0.w, w1.x, w1.y, w1.z, w1.w};
#pragma unroll
            for (int i = 0; i < 4; ++i)
#pragma unroll
                for (int jj = 0; jj < 8; ++jj)
                    acc[i][jj] = fmaf(a_[i], w_[jj], acc[i][jj]);
        }
    }

#pragma unroll
    for (int i = 0; i < 4; ++i) {
        const int rr = (ty << 2) + i;
        if (rr < Mv) {
            *(float4*)(C + (size_t)rr * ldc + (tx << 2)) =
                make_float4(acc[i][0], acc[i][1], acc[i][2], acc[i][3]);
            *(float4*)(C + (size_t)rr * ldc + 64 + (tx << 2)) =
                make_float4(acc[i][4], acc[i][5], acc[i][6], acc[i][7]);
        }
    }
}

// ---------------------------------------------------------------------------
// Narrow router region: C(64 x 4 slice) = A(64 rows x 256) @ Wr(256 x 4).
// Thread t: row = row0 + t/4, col = t&3.  Wr staged transposed in LDS.
__device__ __forceinline__ void router_region(
    const float* __restrict__ A, const float* __restrict__ Wr,
    float* __restrict__ C, int ldc, int row0)
{
    __shared__ float WrT[4][260];
    const int tid = threadIdx.x;
    for (int idx = tid; idx < 1024; idx += 256) {
        const int k = idx >> 2, c = idx & 3;
        WrT[c][k] = Wr[idx];
    }
    __syncthreads();
    const int row = row0 + (tid >> 2), c = tid & 3;
    const float* a = A + (size_t)row * 256;
    float acc = 0.f;
#pragma unroll 8
    for (int k4 = 0; k4 < 64; ++k4) {
        const float4 avv = *(const float4*)(a + (k4 << 2));
        const float4 wvv = *(const float4*)&WrT[c][k4 << 2];
        acc = fmaf(avv.x, wvv.x, acc);
        acc = fmaf(avv.y, wvv.y, acc);
        acc = fmaf(avv.z, wvv.z, acc);
        acc = fmaf(avv.w, wvv.w, acc);
    }
    C[(size_t)row * ldc + c] = acc;
}

// ---------------------------------------------------------------------------
// gemm_main: KVb = keyval @ [W_k|W_v|Wg|W_router]  (2048 x 832, no q!)
//            cond = query @ W_cond                 (512 x 256)
//            qlast = keyval[:,255,:] @ W_q         (8 x 256)
// Flattened region decode, 242 blocks total (~1/CU).
__global__ __launch_bounds__(256) void gemm_main(
    const float* __restrict__ keyval, const float* __restrict__ query,
    const float* __restrict__ W_k, const float* __restrict__ W_v,
    const float* __restrict__ Wg, const float* __restrict__ W_cond,
    const float* __restrict__ W_q, const float* __restrict__ W_router,
    float* __restrict__ KVb, float* __restrict__ cond,
    float* __restrict__ qlast)
{
    const int id = blockIdx.x;
    if (id < 242 - 32) {
        const float* A; int lda, Mv; const float* Bm; int bn; float* C; int ldc;
        if (id < 192) {                       // keyval @ {W_k,W_v,Wg}
            const int rt = id / 6, ct = id % 6;
            const float* Bsel; int cbase;
            if (ct < 2)      { Bsel = W_k; cbase = 0; }
            else if (ct < 4) { Bsel = W_v; cbase = 256; }
            else             { Bsel = Wg;  cbase = 512; }
            A = keyval + (size_t)rt * 64 * 256; lda = 256; Mv = 64;
            Bm = Bsel; bn = (ct & 1) * 128;
            C = KVb + (size_t)rt * 64 * SKV + cbase + bn; ldc = SKV;
        } else if (id < 208) {                // query @ W_cond
            const int t = id - 192, rt = t >> 1, ct = t & 1;
            A = query + (size_t)rt * 64 * 256; lda = 256; Mv = 64;
            Bm = W_cond; bn = ct * 128;
            C = cond + (size_t)rt * 64 * 256 + ct * 128; ldc = 256;
        } else {                              // keyval last rows @ W_q (8 rows)
            const int ct = id - 208;
            A = keyval + 255 * 256; lda = Kk * Dd; Mv = 8;
            Bm = W_q; bn = ct * 128;
            C = qlast + ct * 128; ldc = 256;
        }
        gemm_tile(A, lda, Mv, Bm, 256, bn, C, ldc);
    } else {                                  // keyval @ W_router -> KVb cols 768..771
        router_region(keyval, W_router, KVb + 768, SKV, (id - 210) * 64);
    }
}

// ---------------------------------------------------------------------------
// gemm_cb: Cb = cond @ [W_q|W_k|W_v|Wg|W_router]  (512 x 1088). 72 blocks.
__global__ __launch_bounds__(256) void gemm_cb(
    const float* __restrict__ cond,
    const float* __restrict__ W_q, const float* __restrict__ W_k,
    const float* __restrict__ W_v, const float* __restrict__ Wg,
    const float* __restrict__ W_router, float* __restrict__ Cb)
{
    const int id = blockIdx.x;
    if (id < 64) {
        const int rg = id >> 4, t = id & 15, rt = t >> 1, ct = t & 1;
        const float* Bsel = (rg == 0) ? W_q : (rg == 1) ? W_k : (rg == 2) ? W_v : Wg;
        gemm_tile(cond + (size_t)rt * 64 * 256, 256, 64,
                  Bsel, 256, ct * 128,
                  Cb + (size_t)rt * 64 * SCB + rg * 256 + ct * 128, SCB);
    } else {
        router_region(cond, W_router, Cb + 1024, SCB, (id - 64) * 64);
    }
}

// ---------------------------------------------------------------------------
// Fused router + gated linear-attention recurrence + RMSNorm + W_o projection.
// One block per n (512 blocks, 256 threads), XCD-swizzled so each XCD's L2
// holds exactly one batch's KVb slice. Thread j owns channel c = j.
// Per-t cost cut vs previous: dg = exp(-ln(1+e^-x)/16) (inf-safe, no
// fmin/fabs guards), mask+selection flags precomputed per t in LDS and
// applied via fmaf(flag, dg-1, 1), ql*kk folded to one fma.
__global__ __launch_bounds__(256) void mom_fused(
    const float* __restrict__ KVb, const float* __restrict__ Cb,
    const float* __restrict__ qlast, const float* __restrict__ b_gk2,
    const int* __restrict__ mask, const float* __restrict__ W_o,
    const float* __restrict__ norm_w, float* __restrict__ out,
    float* __restrict__ logits)
{
    __shared__ float4 wm[Kk];             // router weights per t
    __shared__ float4 sw[Kk];             // selection*mask flags per t
    __shared__ float  smf[Kk];            // mask per t
    __shared__ float  Ptile[4][16][68];   // per-wave 16t x 64c, padded row
    __shared__ float  sbuf[4][16];
    __shared__ float  onorm[Dd];

    const int bid = blockIdx.x;
    const int n = ((bid & 7) << 6) | (bid >> 3);   // XCD swizzle: b = bid & 7
    const int b = n >> 6;
    const int j = threadIdx.x;
    const int lane = j & 63;
    const int wv = j >> 6;

    // ---- per-n cond-side values
    const float qc = Cb[(size_t)n * SCB + j];
    const float kc = Cb[(size_t)n * SCB + 256 + j];
    const float vc = Cb[(size_t)n * SCB + 512 + j];
    const float pc = Cb[(size_t)n * SCB + 768 + j] + b_gk2[j];
    const float4 rc = *(const float4*)(Cb + (size_t)n * SCB + 1024);

    const int* pm = mask + b * Kk;

    // ---- router top-2 for t = j; logits out; weights+flags to LDS
    {
        const float4 kvr = *(const float4*)(KVb + (size_t)(b * Kk + j) * SKV + 768);
        float l[4] = {kvr.x + rc.x, kvr.y + rc.y, kvr.z + rc.z, kvr.w + rc.w};
        *(float4*)(logits + ((size_t)n * Kk + j) * 4) = make_float4(l[0], l[1], l[2], l[3]);

        int i1 = 0;
#pragma unroll
        for (int q = 1; q < 4; ++q) if (l[q] > l[i1]) i1 = q;
        int i2 = -1;
#pragma unroll
        for (int q = 0; q < 4; ++q) {
            if (q == i1) continue;
            if (i2 < 0 || l[q] > l[i2]) i2 = q;
        }
        const float mx = fmaxf(l[i1], l[i2]);
        const float e1 = __expf(l[i1] - mx);
        const float e2 = __expf(l[i2] - mx);
        const float inv = 1.f / (e1 + e2);
        float w[4] = {0.f, 0.f, 0.f, 0.f};
        w[i1] = e1 * inv;
        w[i2] = e2 * inv;
        wm[j] = make_float4(w[0], w[1], w[2], w[3]);
        const float mfj = (float)pm[j];
        smf[j] = mfj;
        sw[j] = make_float4(w[0] > 0.f ? mfj : 0.f, w[1] > 0.f ? mfj : 0.f,
                            w[2] > 0.f ? mfj : 0.f, w[3] > 0.f ? mfj : 0.f);
    }
    __syncthreads();

    // ---- reverse-sweep recurrence in 16-t tiles
    const float ql  = qlast[b * Dd + j] + qc;
    const float qkc = ql * kc;
    const float* pkv = KVb + (size_t)b * Kk * SKV + j;

    float E0 = 1.f, E1 = 1.f, E2 = 1.f, E3 = 1.f, E4 = 1.f;
    float o = 0.f;
    const int tl = lane & 15, qq = lane >> 4;

    for (int t0 = Kk - 16; t0 >= 0; t0 -= 16) {
        float vreg[16];
        // phase A: per-t P into LDS tile, straight-line (no branches)
#pragma unroll
        for (int i = 0; i < 16; ++i) {
            const int t = t0 + 15 - i;               // descending t
            const float* r = pkv + (size_t)t * SKV;
            const float kraw = r[0];
            const float vraw = r[256];
            const float praw = r[512];
            const float pre = praw + pc;
            // dg = sigmoid(pre)^(1/16); inf-safe without fmin/fabs guards:
            //   pre->-inf: e=inf, log(inf)=inf, exp(-inf)=0   (correct)
            //   pre->+inf: e=0,  log(1)=0,    exp(0)=1        (correct)
            const float ee = __expf(-pre);
            const float dg = __expf(-0.0625f * __logf(1.0f + ee));
            const float4 w  = wm[t];
            const float4 s4 = sw[t];
            const float mf  = smf[t];
            const float zf = E0 + w.x * E1 + w.y * E2 + w.z * E3 + w.w * E4;
            const float qlk = fmaf(ql, kraw, qkc);
            Ptile[wv][i][lane] = qlk * zf * mf;
            vreg[i] = vraw + vc;
            const float d1 = dg - 1.0f;
            E0 *= fmaf(mf,   d1, 1.0f);
            E1 *= fmaf(s4.x, d1, 1.0f);
            E2 *= fmaf(s4.y, d1, 1.0f);
            E3 *= fmaf(s4.z, d1, 1.0f);
            E4 *= fmaf(s4.w, d1, 1.0f);
        }
        __builtin_amdgcn_wave_barrier();

        // phase B (wave-local): s[i] = sum_c P[i][c]
        float s = 0.f;
#pragma unroll
        for (int rr = 0; rr < 4; ++rr) {
            const float4 p4 = *(const float4*)&Ptile[wv][tl][qq * 16 + rr * 4];
            s += (p4.x + p4.y) + (p4.z + p4.w);
        }
        s += __shfl_xor(s, 16, 64);
        s += __shfl_xor(s, 32, 64);
        sbuf[wv][tl] = s;                 // same-value multi-write, benign
        __builtin_amdgcn_wave_barrier();
#pragma unroll
        for (int rr = 0; rr < 4; ++rr) {
            const float4 sv = *(const float4*)&sbuf[wv][rr * 4];
            o = fmaf(sv.x, vreg[rr * 4 + 0], o);
            o = fmaf(sv.y, vreg[rr * 4 + 1], o);
            o = fmaf(sv.z, vreg[rr * 4 + 2], o);
            o = fmaf(sv.w, vreg[rr * 4 + 3], o);
        }
    }

    // ---- fused RMSNorm over DV (per head = per wave)
    const float ms = wred(o * o) * (1.0f / 64.0f);
    onorm[j] = o * rsqrtf(ms + EPSf) * norm_w[lane];
    __syncthreads();

    // ---- fused output projection: out[n,j] = onorm . W_o[:,j]
    float acc = 0.f;
#pragma unroll 8
    for (int k = 0; k < Dd; ++k)
        acc = fmaf(onorm[k], W_o[(size_t)k * Dd + j], acc);
    out[(size_t)n * Dd + j] = acc;
}

// ---------------------------------------------------------------------------
extern "C" void kernel_launch(void* const* d_in, const int* in_sizes, int n_in,
                              void* d_out, int out_size, void* d_ws, size_t ws_size,
                              hipStream_t stream)
{
    const float* query    = (const float*)d_in[0];   // (8,64,256)
    const float* keyval   = (const float*)d_in[1];   // (8,256,256)
    const int*   mask     = (const int*)  d_in[2];   // (8,256)
    const float* W_cond   = (const float*)d_in[3];   // (256,256)
    const float* W_q      = (const float*)d_in[4];   // (256,256)
    const float* W_k      = (const float*)d_in[5];   // (256,256)
    const float* W_v      = (const float*)d_in[6];   // (256,256)
    const float* W_gk1    = (const float*)d_in[7];   // (256,16)
    const float* W_gk2    = (const float*)d_in[8];   // (16,256)
    const float* b_gk2    = (const float*)d_in[9];   // (256,)
    const float* W_router = (const float*)d_in[10];  // (256,4)
    const float* norm_w   = (const float*)d_in[11];  // (64,)
    const float* W_o      = (const float*)d_in[12];  // (256,256)

    float* out    = (float*)d_out;        // (8,64,256) = 131072
    float* logits = out + Nn * Dd;        // (N*K, 4)   = 524288

    // workspace layout (floats)
    float* p = (float*)d_ws;
    float* Wg    = p; p += 256 * 256;       // W_gk1 @ W_gk2
    float* KVb   = p; p += 2048 * SKV;      // keyval @ [k|v|p|r]
    float* cond  = p; p += Nn * 256;        // query @ W_cond
    float* qlast = p; p += 8 * 256;         // keyval[:,255,:] @ W_q
    float* Cb    = p; p += Nn * SCB;        // cond @ [q|k|v|p|r]

    // 1) Wg = W_gk1 @ W_gk2 (tiny)
    prep<<<256, dim3(256), 0, stream>>>(W_gk1, W_gk2, Wg);

    // 2) KVb (no q-columns) + cond + qlast, one launch, 242 blocks
    gemm_main<<<242, dim3(256), 0, stream>>>(
        keyval, query, W_k, W_v, Wg, W_cond, W_q, W_router, KVb, cond, qlast);

    // 3) Cb = cond @ [q|k|v|p|r]  (72 blocks)
    gemm_cb<<<72, dim3(256), 0, stream>>>(cond, W_q, W_k, W_v, Wg, W_router, Cb);

    // 4) router + recurrence + RMSNorm + output projection
    mom_fused<<<Nn, dim3(256), 0, stream>>>(
        KVb, Cb, qlast, b_gk2, mask, W_o, norm_w, out, logits);
}